// Round 2
// 645.057 us; speedup vs baseline: 1.1948x; 1.1948x over previous
//
#include <hip/hip_runtime.h>

#define Mdim 4096
#define Kdim 4096
#define Ndim 12288

typedef __bf16 bf16x8 __attribute__((ext_vector_type(8)));
typedef float f32x4 __attribute__((ext_vector_type(4)));
typedef unsigned short u16x8 __attribute__((ext_vector_type(8)));
typedef int i32x4 __attribute__((ext_vector_type(4)));

__device__ __forceinline__ unsigned short f2bf(float f) {
    unsigned int u = __builtin_bit_cast(unsigned int, f);
    u += 0x7FFFu + ((u >> 16) & 1u);       // RNE
    return (unsigned short)(u >> 16);
}

typedef __attribute__((address_space(1))) void gvoid_t;
typedef __attribute__((address_space(3))) void lvoid_t;
__device__ __forceinline__ void gld16(const void* g, void* l) {
    // 16B per lane, LDS dest = wave-uniform base + lane*16
    __builtin_amdgcn_global_load_lds((gvoid_t*)g, (lvoid_t*)l, 16, 0, 0);
}

// ---------------------------------------------------------------------------
// Kernel 0: A fp32 -> bf16 with K-permutation folded in (unchanged).
// ---------------------------------------------------------------------------
__global__ __launch_bounds__(256) void permute_convert_a_kernel(
    const float* __restrict__ A, const int* __restrict__ invperm,
    unsigned short* __restrict__ Ab)
{
    __shared__ unsigned short rowbuf[2][Kdim];
    const int tid = threadIdx.x;
    const int m0 = blockIdx.x * 2;
#pragma unroll
    for (int c = 0; c < 4; ++c) {
        const int i = (c * 256 + tid) * 4;
        const i32x4 ip = *(const i32x4*)&invperm[i];
        const f32x4 v0 = *(const f32x4*)&A[(size_t)m0 * Kdim + i];
        const f32x4 v1 = *(const f32x4*)&A[(size_t)(m0 + 1) * Kdim + i];
#pragma unroll
        for (int u = 0; u < 4; ++u) {
            rowbuf[0][ip[u]] = f2bf(v0[u]);
            rowbuf[1][ip[u]] = f2bf(v1[u]);
        }
    }
    __syncthreads();
#pragma unroll
    for (int r = 0; r < 2; ++r)
#pragma unroll
        for (int c = 0; c < 2; ++c) {
            const int j = (c * 256 + tid) * 8;
            const u16x8 o = *(const u16x8*)&rowbuf[r][j];
            *(u16x8*)&Ab[(size_t)(m0 + r) * Kdim + j] = o;
        }
}

// ---------------------------------------------------------------------------
// Kernel 1: dequant in natural k-order (unchanged).
// ---------------------------------------------------------------------------
__global__ __launch_bounds__(256) void dequant_kernel(
    const int* __restrict__ qw,              // [K/8][N]
    const int* __restrict__ qs,              // [G][N/8]
    const float* __restrict__ qsm,           // [G] fp32
    unsigned short* __restrict__ Wt)         // [N][K] bf16 bits
{
    __shared__ unsigned short tile[64 * 72];
    const int k0 = blockIdx.x * 64;
    const int n0 = blockIdx.y * 64;
    const int g = k0 >> 7;
    const int tid = threadIdx.x;
    const int n_l = tid & 63;
    const int kb_l = tid >> 6;
    const int n = n0 + n_l;
    const int sw = qs[g * (Ndim / 8) + (n >> 3)];
    const int sc = (sw >> ((n & 7) * 4)) & 0xF;
    const float scale = (float)((sc + 1) * (sc + 1)) * qsm[g];
#pragma unroll
    for (int ii = 0; ii < 2; ++ii) {
        const int kb = kb_l + ii * 4;
        const int w = qw[(size_t)(k0 / 8 + kb) * Ndim + n];
        u16x8 o;
#pragma unroll
        for (int u = 0; u < 8; ++u)
            o[u] = f2bf((float)(((w >> (4 * u)) & 0xF) - 8) * scale);
        *(u16x8*)&tile[n_l * 72 + kb * 8] = o;
    }
    __syncthreads();
#pragma unroll
    for (int cc = 0; cc < 2; ++cc) {
        const int c = tid + cc * 256;
        const int row = c >> 3, part = c & 7;
        const u16x8 v = *(const u16x8*)&tile[row * 72 + part * 8];
        *(u16x8*)&Wt[(size_t)(n0 + row) * Kdim + k0 + part * 8] = v;
    }
}

// ---------------------------------------------------------------------------
// Kernel 2: bf16 GEMM, 256x256 tile, BK=64, 8 waves, 8-phase schedule with
// counted vmcnt (T2+T3+T4+T5).  C[M][N] = Ab[M][K] * Wt[N][K]^T + bias.
//
// LDS: per operand a ring of 4 K-half regions (256 rows x 32 k = 16 KiB),
//   tile t kstep0 -> slot (2t)&3, kstep1 -> slot (2t+1)&3.
// Row = 64 B = 4 x 16B chunks; chunk swizzle: c_phys = c_log ^ f(row),
//   f(row) = (row&3)^((row>>2)&3).  global_load_lds writes linearly, so the
//   SOURCE k-chunk is pre-swizzled per thread; ds_reads apply the same XOR.
//   -> every consecutive 8-lane group of a frag b128 read hits 8 distinct
//   16B slots: conflict-free.
// Per K-tile (4 phases): P1 [ldA(mh0,s0)+ldB(s0) | stage A-Kh1(t+1) | bar |
//   16 mfma | bar], P2 [ldA(mh1,s0) | stage B-Kh1(t+1) | vmcnt(8) | bar |
//   16 mfma | bar], P3/P4 same on s1, staging Kh0(t+2) into slot (2t)&3.
// FIFO at each vmcnt(8) = 12 outstanding; the 4 completed are exactly the
//   half-regions read next, issued 4-5 phases earlier (latency covered).
// Every stage's dest slot was last ds_read >=1 barrier-pair before issue.
// ---------------------------------------------------------------------------
#define BAR()    asm volatile("s_barrier" ::: "memory")
#define VMCNT8() asm volatile("s_waitcnt vmcnt(8)" ::: "memory")

#define STAGE(dstW, src, slot, koff) do {                                   \
    gld16((src) + (koff), (dstW) + (slot) * 8192);                          \
    gld16((src) + (koff) + rstep, (dstW) + (slot) * 8192 + 4096); } while (0)

#define LD_A(slot, mh) do {                                                 \
    const unsigned short* p_ = &As[slot][aBase + (mh) * 2048];              \
    af[0] = *(const bf16x8*)(p_);                                           \
    af[1] = *(const bf16x8*)(p_ + 512);                                     \
    af[2] = *(const bf16x8*)(p_ + 1024);                                    \
    af[3] = *(const bf16x8*)(p_ + 1536); } while (0)

#define LD_B(slot) do {                                                     \
    const unsigned short* p_ = &Bs[slot][bBase];                            \
    bf[0] = *(const bf16x8*)(p_);                                           \
    bf[1] = *(const bf16x8*)(p_ + 512);                                     \
    bf[2] = *(const bf16x8*)(p_ + 1024);                                    \
    bf[3] = *(const bf16x8*)(p_ + 1536); } while (0)

#define MFMA_HALF(mh) do {                                                  \
    __builtin_amdgcn_s_setprio(1);                                          \
    _Pragma("unroll")                                                       \
    for (int i_ = 0; i_ < 4; ++i_)                                          \
      _Pragma("unroll")                                                     \
      for (int j_ = 0; j_ < 4; ++j_)                                        \
        acc[(mh) * 4 + i_][j_] = __builtin_amdgcn_mfma_f32_16x16x32_bf16(   \
            af[i_], bf[j_], acc[(mh) * 4 + i_][j_], 0, 0, 0);               \
    __builtin_amdgcn_s_setprio(0); } while (0)

__global__ __launch_bounds__(512, 2) void gemm_bf16_256_kernel(
    const unsigned short* __restrict__ A,    // x-permuted [M][K] bf16 bits
    const unsigned short* __restrict__ Bt,   // Wt [N][K] bf16 bits
    const float* __restrict__ bias,          // [N] fp32
    float* __restrict__ C)                   // [M][N] fp32
{
    __shared__ __attribute__((aligned(16))) unsigned short As[4][8192];
    __shared__ __attribute__((aligned(16))) unsigned short Bs[4][8192];

    const int tid = threadIdx.x;
    const int lane = tid & 63, wave = tid >> 6;
    const int wm = wave >> 2, wn = wave & 3;

    // bijective XCD swizzle: 768 wgs = 8 XCDs x 96. Chunk spans all 16 bm x
    // 6 bn -> each B panel L2-resident per XCD, A panels recycle via L3.
    const int wgid = (blockIdx.x & 7) * 96 + (blockIdx.x >> 3);
    const int bm = wgid & 15;    // 0..15  (M/256)
    const int bn = wgid >> 4;    // 0..47  (N/256)

    // ---- staging (thread t covers region row t>>2, rows +128 on 2nd load) --
    const int srow = tid >> 2;                                  // 0..127
    const int fs = (srow & 3) ^ ((srow >> 2) & 3);
    const int gcg = ((tid & 3) ^ fs) * 8;                       // pre-swz chunk
    const unsigned short* Ag = A + (size_t)(bm * 256 + srow) * Kdim + gcg;
    const unsigned short* Bg = Bt + (size_t)(bn * 256 + srow) * Kdim + gcg;
    const size_t rstep = (size_t)128 * Kdim;
    unsigned short* AsW = &As[0][0] + wave * 512;   // wave-uniform dest base
    unsigned short* BsW = &Bs[0][0] + wave * 512;

    // ---- fragment read addresses (swizzled) ----
    const int fr = (lane & 3) ^ ((lane >> 2) & 3);
    const int pcg = ((lane >> 4) ^ fr) * 8;
    const int aBase = (wm * 128 + (lane & 15)) * 32 + pcg;
    const int bBase = (wn * 64 + (lane & 15)) * 32 + pcg;

    f32x4 acc[8][4];
    const f32x4 zero = {0.f, 0.f, 0.f, 0.f};
#pragma unroll
    for (int i = 0; i < 8; ++i)
#pragma unroll
        for (int j = 0; j < 4; ++j) acc[i][j] = zero;

    // ---- prologue: A0(0) B0(0) A1(0) B1(0) A0(1) B0(1); drain first 4 ----
    STAGE(AsW, Ag, 0, 0);
    STAGE(BsW, Bg, 0, 0);
    STAGE(AsW, Ag, 1, 32);
    STAGE(BsW, Bg, 1, 32);
    STAGE(AsW, Ag, 2, 64);
    STAGE(BsW, Bg, 2, 64);
    VMCNT8();
    BAR();

    bf16x8 af[4], bf[4];
#pragma unroll 2
    for (int t = 0; t < 64; ++t) {
        const int s0 = (2 * t) & 3, s1 = (2 * t + 1) & 3, sd1 = (2 * t + 3) & 3;
        const int tn1 = (t + 1 < 64 ? t + 1 : 63) * 64;
        const int tn2 = (t + 2 < 64 ? t + 2 : 63) * 64;
        // P1: kstep0, M-half0
        LD_A(s0, 0);
        LD_B(s0);
        STAGE(AsW, Ag, sd1, tn1 + 32);
        BAR();
        MFMA_HALF(0);
        BAR();
        // P2: kstep0, M-half1 (bf reused)
        LD_A(s0, 1);
        STAGE(BsW, Bg, sd1, tn1 + 32);
        VMCNT8();                      // completes A-Kh1(t), B-Kh1(t)
        BAR();
        MFMA_HALF(1);
        BAR();
        // P3: kstep1, M-half0
        LD_A(s1, 0);
        LD_B(s1);
        STAGE(AsW, Ag, s0, tn2);       // overwrite kstep0 slot (reads done P2)
        BAR();
        MFMA_HALF(0);
        BAR();
        // P4: kstep1, M-half1
        LD_A(s1, 1);
        STAGE(BsW, Bg, s0, tn2);
        VMCNT8();                      // completes A-Kh0(t+1), B-Kh0(t+1)
        BAR();
        MFMA_HALF(1);
        BAR();
    }

    // ---- epilogue: C/D layout col = lane&15, row = (lane>>4)*4 + r ----
    const int colb = bn * 256 + wn * 64 + (lane & 15);
    const int rowb = bm * 256 + wm * 128 + (lane >> 4) * 4;
    float bj[4];
#pragma unroll
    for (int j = 0; j < 4; ++j) bj[j] = bias[colb + j * 16];
#pragma unroll
    for (int mf = 0; mf < 8; ++mf)
#pragma unroll
        for (int r = 0; r < 4; ++r) {
            const size_t row = (size_t)(rowb + mf * 16 + r);
#pragma unroll
            for (int j = 0; j < 4; ++j)
                C[row * Ndim + colb + j * 16] = acc[mf][j][r] + bj[j];
        }
}

extern "C" void kernel_launch(void* const* d_in, const int* in_sizes, int n_in,
                              void* d_out, int out_size, void* d_ws, size_t ws_size,
                              hipStream_t stream) {
    const float* input   = (const float*)d_in[0];   // [M][K] fp32 (fp16 promoted)
    const int*   qw      = (const int*)d_in[1];     // [K/8][N]
    const int*   qs      = (const int*)d_in[2];     // [G][N/8]
    const float* qsm     = (const float*)d_in[3];   // [G] fp32
    const int*   invperm = (const int*)d_in[4];     // [K]
    const float* bias    = (const float*)d_in[5];   // [N] fp32 (zeros)
    float*       out     = (float*)d_out;           // [M][N] fp32

    unsigned short* Ab = (unsigned short*)d_ws;                      // 32 MiB
    unsigned short* Wt = (unsigned short*)((char*)d_ws + ((size_t)Mdim * Kdim * 2)); // 96 MiB

    permute_convert_a_kernel<<<Mdim / 2, 256, 0, stream>>>(input, invperm, Ab);
    dequant_kernel<<<dim3(Kdim / 64, Ndim / 64), 256, 0, stream>>>(qw, qs, qsm, Wt);
    gemm_bf16_256_kernel<<<dim3((Mdim / 256) * (Ndim / 256)), 512, 0, stream>>>(
        Ab, Wt, bias, out);
}